// Round 1
// baseline (933.596 us; speedup 1.0000x reference)
//
#include <hip/hip_runtime.h>
#include <math.h>

// GATNet: N=100000 nodes, D=128, HEADS=4, HID=32, OUT_C=64, E=1.6M (+N self-loops)
#define NEG_SLOPE 0.2f

// ---------------- CSR build ----------------

__global__ void zero_kernel(int* __restrict__ p, int n) {
    int i = blockIdx.x * blockDim.x + threadIdx.x;
    if (i < n) p[i] = 0;
}

__global__ void hist_kernel(const int* __restrict__ ei, int E, int E2, int* __restrict__ counts) {
    int e = blockIdx.x * blockDim.x + threadIdx.x;
    if (e >= E2) return;
    int dst = (e < E) ? ei[E + e] : (e - E);   // self-loop tail
    atomicAdd(&counts[dst], 1);
}

// per-256-chunk exclusive scan; chunk totals to bs[]
__global__ void scan1_kernel(const int* __restrict__ counts, int N,
                             int* __restrict__ indptr, int* __restrict__ bs) {
    __shared__ int s[256];
    int t = threadIdx.x;
    int i = blockIdx.x * 256 + t;
    int v = (i < N) ? counts[i] : 0;
    s[t] = v;
    __syncthreads();
    for (int off = 1; off < 256; off <<= 1) {
        int u = (t >= off) ? s[t - off] : 0;
        __syncthreads();
        s[t] += u;
        __syncthreads();
    }
    if (i < N) indptr[i] = s[t] - v;      // exclusive within chunk
    if (t == 255) bs[blockIdx.x] = s[255]; // chunk total
}

// single-block exclusive scan of chunk totals (B <= 512)
__global__ void scan2_kernel(int* __restrict__ bs, int B) {
    __shared__ int s[512];
    int t = threadIdx.x;
    s[t] = (t < B) ? bs[t] : 0;
    __syncthreads();
    for (int off = 1; off < 512; off <<= 1) {
        int u = (t >= off) ? s[t - off] : 0;
        __syncthreads();
        s[t] += u;
        __syncthreads();
    }
    if (t < B) bs[t] = (t == 0) ? 0 : s[t - 1];
}

__global__ void scan3_kernel(int* __restrict__ indptr, int* __restrict__ cursor,
                             const int* __restrict__ bs, int N) {
    int i = blockIdx.x * blockDim.x + threadIdx.x;
    if (i >= N) return;
    int v = indptr[i] + bs[i >> 8];
    indptr[i] = v;
    cursor[i] = v;
}

__global__ void scatter_kernel(const int* __restrict__ ei, int E, int E2,
                               int* __restrict__ cursor, int* __restrict__ csr_src) {
    int e = blockIdx.x * blockDim.x + threadIdx.x;
    if (e >= E2) return;
    int src, dst;
    if (e < E) { src = ei[e]; dst = ei[E + e]; }
    else       { src = e - E; dst = e - E; }
    int pos = atomicAdd(&cursor[dst], 1);
    csr_src[pos] = src;
}

// ---------------- Layer 1 GEMM: h1 = emb[xidx] @ W1  [N,128]x[128,128] ----------------

__global__ void gemm1_kernel(const float* __restrict__ emb, const int* __restrict__ xidx,
                             const float* __restrict__ W1, float* __restrict__ h1, int N) {
    __shared__ float xs[2 * 128];
    int lr = threadIdx.x >> 7;       // 0..1
    int lc = threadIdx.x & 127;      // 0..127
    int row = blockIdx.x * 2 + lr;
    if (row < N) {
        int s = xidx[row];
        xs[lr * 128 + lc] = emb[(size_t)s * 128 + lc];
    }
    __syncthreads();
    if (row >= N) return;
    float acc = 0.f;
#pragma unroll 8
    for (int k = 0; k < 128; k++) {
        acc = fmaf(xs[lr * 128 + k], W1[k * 128 + lc], acc);
    }
    h1[(size_t)row * 128 + lc] = acc;
}

// ---------------- Layer 2 GEMM: h2 = x1 @ W2  [N,128]x[128,64] ----------------

__global__ void gemm2_kernel(const float* __restrict__ x1, const float* __restrict__ W2,
                             float* __restrict__ h2, int N) {
    __shared__ float xs[4 * 128];
    int lr = threadIdx.x >> 6;       // 0..3
    int lc = threadIdx.x & 63;       // 0..63
    int r0 = blockIdx.x * 4;
    for (int i = threadIdx.x; i < 512; i += 256) {
        int rr = i >> 7, cc = i & 127;
        xs[i] = (r0 + rr < N) ? x1[(size_t)(r0 + rr) * 128 + cc] : 0.f;
    }
    __syncthreads();
    int row = r0 + lr;
    if (row >= N) return;
    float acc = 0.f;
#pragma unroll 8
    for (int k = 0; k < 128; k++) {
        acc = fmaf(xs[lr * 128 + k], W2[k * 64 + lc], acc);
    }
    h2[(size_t)row * 64 + lc] = acc;
}

// ---------------- attention logits ----------------

__global__ void alpha1_kernel(const float* __restrict__ h1, const float* __restrict__ aw,
                              const float* __restrict__ dw, float* __restrict__ as1,
                              float* __restrict__ ad1, int N) {
    int t = blockIdx.x * blockDim.x + threadIdx.x;
    if (t >= N * 4) return;
    int n = t >> 2, h = t & 3;
    const float4* hp = (const float4*)(h1 + (size_t)n * 128 + h * 32);
    const float4* ap = (const float4*)(aw + h * 32);
    const float4* dp = (const float4*)(dw + h * 32);
    float s = 0.f, d = 0.f;
#pragma unroll
    for (int j = 0; j < 8; j++) {
        float4 v = hp[j], a = ap[j], dd = dp[j];
        s += v.x * a.x + v.y * a.y + v.z * a.z + v.w * a.w;
        d += v.x * dd.x + v.y * dd.y + v.z * dd.z + v.w * dd.w;
    }
    as1[t] = s;
    ad1[t] = d;
}

__global__ void alpha2_kernel(const float* __restrict__ h2, const float* __restrict__ aw,
                              const float* __restrict__ dw, float* __restrict__ as2,
                              float* __restrict__ ad2, int N) {
    int n = blockIdx.x * blockDim.x + threadIdx.x;
    if (n >= N) return;
    const float4* hp = (const float4*)(h2 + (size_t)n * 64);
    float s = 0.f, d = 0.f;
#pragma unroll
    for (int j = 0; j < 16; j++) {
        float4 v = hp[j];
        float4 a = ((const float4*)aw)[j];
        float4 dd = ((const float4*)dw)[j];
        s += v.x * a.x + v.y * a.y + v.z * a.z + v.w * a.w;
        d += v.x * dd.x + v.y * dd.y + v.z * dd.z + v.w * dd.w;
    }
    as2[n] = s;
    ad2[n] = d;
}

// ---------------- aggregation: online softmax per dst node ----------------

__global__ void __launch_bounds__(128)
agg1_kernel(const int* __restrict__ csr, const int* __restrict__ indptr,
            const int* __restrict__ counts, const float* __restrict__ as1,
            const float* __restrict__ ad1, const float* __restrict__ h1,
            const float* __restrict__ b1, float* __restrict__ x1, int N) {
    int n = blockIdx.x;
    int c = threadIdx.x;       // 0..127
    int h = c >> 5;            // head
    int start = indptr[n];
    int cnt = counts[n];
    float ad = ad1[n * 4 + h];
    float m = -INFINITY, l = 0.f, acc = 0.f;
    int src = csr[start];
    for (int i = 0; i < cnt; i++) {
        int nsrc = (i + 1 < cnt) ? csr[start + i + 1] : 0;
        float e = as1[src * 4 + h] + ad;
        e = (e > 0.f) ? e : NEG_SLOPE * e;
        float mn = fmaxf(m, e);
        float cf = __expf(m - mn);   // m=-inf first iter -> 0
        float p = __expf(e - mn);
        l = l * cf + p;
        acc = acc * cf + p * h1[(size_t)src * 128 + c];
        m = mn;
        src = nsrc;
    }
    float o = acc / l + b1[c];
    // ELU (alpha=1)
    x1[(size_t)n * 128 + c] = (o > 0.f) ? o : (__expf(o) - 1.f);
}

__global__ void __launch_bounds__(64)
agg2_kernel(const int* __restrict__ csr, const int* __restrict__ indptr,
            const int* __restrict__ counts, const float* __restrict__ as2,
            const float* __restrict__ ad2, const float* __restrict__ h2,
            const float* __restrict__ b2, float* __restrict__ out, int N) {
    int n = blockIdx.x;
    int c = threadIdx.x;       // 0..63
    int start = indptr[n];
    int cnt = counts[n];
    float ad = ad2[n];
    float m = -INFINITY, l = 0.f, acc = 0.f;
    int src = csr[start];
    for (int i = 0; i < cnt; i++) {
        int nsrc = (i + 1 < cnt) ? csr[start + i + 1] : 0;
        float e = as2[src] + ad;
        e = (e > 0.f) ? e : NEG_SLOPE * e;
        float mn = fmaxf(m, e);
        float cf = __expf(m - mn);
        float p = __expf(e - mn);
        l = l * cf + p;
        acc = acc * cf + p * h2[(size_t)src * 64 + c];
        m = mn;
        src = nsrc;
    }
    out[(size_t)n * 64 + c] = acc / l + b2[c];
}

// ---------------- launcher ----------------

extern "C" void kernel_launch(void* const* d_in, const int* in_sizes, int n_in,
                              void* d_out, int out_size, void* d_ws, size_t ws_size,
                              hipStream_t stream) {
    const int*   xidx = (const int*)d_in[0];
    const int*   ei   = (const int*)d_in[1];
    const float* emb  = (const float*)d_in[2];
    const float* W1   = (const float*)d_in[3];
    const float* a_s1 = (const float*)d_in[4];
    const float* a_d1 = (const float*)d_in[5];
    const float* b1   = (const float*)d_in[6];
    const float* W2   = (const float*)d_in[7];
    const float* a_s2 = (const float*)d_in[8];
    const float* a_d2 = (const float*)d_in[9];
    const float* b2   = (const float*)d_in[10];
    float* out = (float*)d_out;

    const int N  = in_sizes[0];
    const int E  = in_sizes[1] / 2;
    const int E2 = E + N;
    const int B  = (N + 255) / 256;   // scan chunks (391 for N=100000)

    // workspace layout
    int* ws_i   = (int*)d_ws;
    int* counts = ws_i;
    int* indptr = ws_i + N;
    int* cursor = ws_i + 2 * (size_t)N;
    int* bs     = ws_i + 3 * (size_t)N;
    int* csr    = ws_i + 3 * (size_t)N + 512;
    size_t fbase = ((size_t)(3 * (size_t)N + 512 + E2) + 3) & ~(size_t)3;
    float* ws_f = (float*)d_ws;
    float* h1  = ws_f + fbase;                  // N*128
    float* x1  = h1 + (size_t)N * 128;          // N*128
    float* as1 = x1 + (size_t)N * 128;          // N*4
    float* ad1 = as1 + (size_t)N * 4;           // N*4
    float* h2  = h1;   // alias: h1 dead after agg1
    float* as2 = as1;  // alias: as1 dead after agg1
    float* ad2 = ad1;

    // CSR build
    zero_kernel<<<(N + 255) / 256, 256, 0, stream>>>(counts, N);
    hist_kernel<<<(E2 + 255) / 256, 256, 0, stream>>>(ei, E, E2, counts);
    scan1_kernel<<<B, 256, 0, stream>>>(counts, N, indptr, bs);
    scan2_kernel<<<1, 512, 0, stream>>>(bs, B);
    scan3_kernel<<<(N + 255) / 256, 256, 0, stream>>>(indptr, cursor, bs, N);
    scatter_kernel<<<(E2 + 255) / 256, 256, 0, stream>>>(ei, E, E2, cursor, csr);

    // Layer 1
    gemm1_kernel<<<(N + 1) / 2, 256, 0, stream>>>(emb, xidx, W1, h1, N);
    alpha1_kernel<<<(N * 4 + 255) / 256, 256, 0, stream>>>(h1, a_s1, a_d1, as1, ad1, N);
    agg1_kernel<<<N, 128, 0, stream>>>(csr, indptr, counts, as1, ad1, h1, b1, x1, N);

    // Layer 2
    gemm2_kernel<<<(N + 3) / 4, 256, 0, stream>>>(x1, W2, h2, N);
    alpha2_kernel<<<(N + 255) / 256, 256, 0, stream>>>(h2, a_s2, a_d2, as2, ad2, N);
    agg2_kernel<<<N, 64, 0, stream>>>(csr, indptr, counts, as2, ad2, h2, b2, out, N);
}

// Round 2
// 756.859 us; speedup vs baseline: 1.2335x; 1.2335x over previous
//
#include <hip/hip_runtime.h>
#include <math.h>

// GATNet: N=100000 nodes, D=128, HEADS=4, HID=32, OUT_C=64, E=1.6M (+N self-loops)
#define NEG_SLOPE 0.2f

// ---------------- CSR build ----------------

__global__ void zero_kernel(int* __restrict__ p, int n) {
    int i = blockIdx.x * blockDim.x + threadIdx.x;
    if (i < n) p[i] = 0;
}

__global__ void hist_kernel(const int* __restrict__ ei, int E, int E2, int* __restrict__ counts) {
    int e = blockIdx.x * blockDim.x + threadIdx.x;
    if (e >= E2) return;
    int dst = (e < E) ? ei[E + e] : (e - E);   // self-loop tail
    atomicAdd(&counts[dst], 1);
}

// per-256-chunk exclusive scan; chunk totals to bs[]
__global__ void scan1_kernel(const int* __restrict__ counts, int N,
                             int* __restrict__ indptr, int* __restrict__ bs) {
    __shared__ int s[256];
    int t = threadIdx.x;
    int i = blockIdx.x * 256 + t;
    int v = (i < N) ? counts[i] : 0;
    s[t] = v;
    __syncthreads();
    for (int off = 1; off < 256; off <<= 1) {
        int u = (t >= off) ? s[t - off] : 0;
        __syncthreads();
        s[t] += u;
        __syncthreads();
    }
    if (i < N) indptr[i] = s[t] - v;      // exclusive within chunk
    if (t == 255) bs[blockIdx.x] = s[255]; // chunk total
}

// single-block exclusive scan of chunk totals (B <= 512)
__global__ void scan2_kernel(int* __restrict__ bs, int B) {
    __shared__ int s[512];
    int t = threadIdx.x;
    s[t] = (t < B) ? bs[t] : 0;
    __syncthreads();
    for (int off = 1; off < 512; off <<= 1) {
        int u = (t >= off) ? s[t - off] : 0;
        __syncthreads();
        s[t] += u;
        __syncthreads();
    }
    if (t < B) bs[t] = (t == 0) ? 0 : s[t - 1];
}

__global__ void scan3_kernel(int* __restrict__ indptr, int* __restrict__ cursor,
                             const int* __restrict__ bs, int N) {
    int i = blockIdx.x * blockDim.x + threadIdx.x;
    if (i >= N) return;
    int v = indptr[i] + bs[i >> 8];
    indptr[i] = v;
    cursor[i] = v;
}

__global__ void scatter_kernel(const int* __restrict__ ei, int E, int E2,
                               int* __restrict__ cursor, int* __restrict__ csr_src) {
    int e = blockIdx.x * blockDim.x + threadIdx.x;
    if (e >= E2) return;
    int src, dst;
    if (e < E) { src = ei[e]; dst = ei[E + e]; }
    else       { src = e - E; dst = e - E; }
    int pos = atomicAdd(&cursor[dst], 1);
    csr_src[pos] = src;
}

// ---------------- register-tiled fp32 GEMMs ----------------
// gemm1: h1[N,128] = emb[xidx] @ W1[128,128]. Block = 64 rows x 64 cols
// (gridDim.y=2 for the two col halves), 256 threads, 4x4 per thread.
// LDS: xs 32KB + ws 32KB = 64KB -> 2 blocks/CU.

__global__ __launch_bounds__(256) void gemm1_kernel(const float* __restrict__ emb,
                             const int* __restrict__ xidx,
                             const float* __restrict__ W1, float* __restrict__ h1, int N) {
    __shared__ float xs[64][128];
    __shared__ float ws[128][64];
    int tid = threadIdx.x;
    int r0 = blockIdx.x * 64;
    int c0 = blockIdx.y * 64;
    {   // stage W1 cols [c0, c0+64)
        const float4* W4 = (const float4*)W1;   // row stride 32 float4
        float4* ws4 = (float4*)ws;              // row stride 16 float4
        int cbase = c0 >> 2;
        for (int i = tid; i < 128 * 16; i += 256) {
            int k = i >> 4, c = i & 15;
            ws4[i] = W4[k * 32 + cbase + c];
        }
    }
    {   // stage x rows [r0, r0+64) with embedding gather
        float4* xs4 = (float4*)xs;
        for (int i = tid; i < 64 * 32; i += 256) {
            int r = i >> 5, c = i & 31;
            int row = r0 + r;
            float4 v = make_float4(0.f, 0.f, 0.f, 0.f);
            if (row < N) {
                int s = xidx[row];
                v = ((const float4*)emb)[(size_t)s * 32 + c];
            }
            xs4[i] = v;
        }
    }
    __syncthreads();
    int tr = tid >> 4;   // 0..15 -> rows tr*4..tr*4+3
    int tc = tid & 15;   // 0..15 -> cols tc*4..tc*4+3
    float4 acc[4];
    acc[0] = acc[1] = acc[2] = acc[3] = make_float4(0.f, 0.f, 0.f, 0.f);
    for (int k = 0; k < 128; k += 4) {
        float4 wv0 = *(const float4*)&ws[k][tc * 4];
        float4 wv1 = *(const float4*)&ws[k + 1][tc * 4];
        float4 wv2 = *(const float4*)&ws[k + 2][tc * 4];
        float4 wv3 = *(const float4*)&ws[k + 3][tc * 4];
#pragma unroll
        for (int i = 0; i < 4; i++) {
            float4 xv = *(const float4*)&xs[tr * 4 + i][k];
            acc[i].x = fmaf(xv.x, wv0.x, acc[i].x);
            acc[i].y = fmaf(xv.x, wv0.y, acc[i].y);
            acc[i].z = fmaf(xv.x, wv0.z, acc[i].z);
            acc[i].w = fmaf(xv.x, wv0.w, acc[i].w);
            acc[i].x = fmaf(xv.y, wv1.x, acc[i].x);
            acc[i].y = fmaf(xv.y, wv1.y, acc[i].y);
            acc[i].z = fmaf(xv.y, wv1.z, acc[i].z);
            acc[i].w = fmaf(xv.y, wv1.w, acc[i].w);
            acc[i].x = fmaf(xv.z, wv2.x, acc[i].x);
            acc[i].y = fmaf(xv.z, wv2.y, acc[i].y);
            acc[i].z = fmaf(xv.z, wv2.z, acc[i].z);
            acc[i].w = fmaf(xv.z, wv2.w, acc[i].w);
            acc[i].x = fmaf(xv.w, wv3.x, acc[i].x);
            acc[i].y = fmaf(xv.w, wv3.y, acc[i].y);
            acc[i].z = fmaf(xv.w, wv3.z, acc[i].z);
            acc[i].w = fmaf(xv.w, wv3.w, acc[i].w);
        }
    }
#pragma unroll
    for (int i = 0; i < 4; i++) {
        int row = r0 + tr * 4 + i;
        if (row < N) *(float4*)&h1[(size_t)row * 128 + c0 + tc * 4] = acc[i];
    }
}

// gemm2: h2[N,64] = x1[N,128] @ W2[128,64]. Block = 64 rows x 64 cols.
__global__ __launch_bounds__(256) void gemm2_kernel(const float* __restrict__ x1,
                             const float* __restrict__ W2,
                             float* __restrict__ h2, int N) {
    __shared__ float xs[64][128];
    __shared__ float ws[128][64];
    int tid = threadIdx.x;
    int r0 = blockIdx.x * 64;
    {   // stage all of W2
        const float4* W4 = (const float4*)W2;
        float4* ws4 = (float4*)ws;
        for (int i = tid; i < 128 * 16; i += 256) ws4[i] = W4[i];
    }
    {   // stage x rows
        float4* xs4 = (float4*)xs;
        for (int i = tid; i < 64 * 32; i += 256) {
            int r = i >> 5, c = i & 31;
            int row = r0 + r;
            float4 v = make_float4(0.f, 0.f, 0.f, 0.f);
            if (row < N) v = ((const float4*)x1)[(size_t)row * 32 + c];
            xs4[i] = v;
        }
    }
    __syncthreads();
    int tr = tid >> 4;
    int tc = tid & 15;
    float4 acc[4];
    acc[0] = acc[1] = acc[2] = acc[3] = make_float4(0.f, 0.f, 0.f, 0.f);
    for (int k = 0; k < 128; k += 4) {
        float4 wv0 = *(const float4*)&ws[k][tc * 4];
        float4 wv1 = *(const float4*)&ws[k + 1][tc * 4];
        float4 wv2 = *(const float4*)&ws[k + 2][tc * 4];
        float4 wv3 = *(const float4*)&ws[k + 3][tc * 4];
#pragma unroll
        for (int i = 0; i < 4; i++) {
            float4 xv = *(const float4*)&xs[tr * 4 + i][k];
            acc[i].x = fmaf(xv.x, wv0.x, acc[i].x);
            acc[i].y = fmaf(xv.x, wv0.y, acc[i].y);
            acc[i].z = fmaf(xv.x, wv0.z, acc[i].z);
            acc[i].w = fmaf(xv.x, wv0.w, acc[i].w);
            acc[i].x = fmaf(xv.y, wv1.x, acc[i].x);
            acc[i].y = fmaf(xv.y, wv1.y, acc[i].y);
            acc[i].z = fmaf(xv.y, wv1.z, acc[i].z);
            acc[i].w = fmaf(xv.y, wv1.w, acc[i].w);
            acc[i].x = fmaf(xv.z, wv2.x, acc[i].x);
            acc[i].y = fmaf(xv.z, wv2.y, acc[i].y);
            acc[i].z = fmaf(xv.z, wv2.z, acc[i].z);
            acc[i].w = fmaf(xv.z, wv2.w, acc[i].w);
            acc[i].x = fmaf(xv.w, wv3.x, acc[i].x);
            acc[i].y = fmaf(xv.w, wv3.y, acc[i].y);
            acc[i].z = fmaf(xv.w, wv3.z, acc[i].z);
            acc[i].w = fmaf(xv.w, wv3.w, acc[i].w);
        }
    }
#pragma unroll
    for (int i = 0; i < 4; i++) {
        int row = r0 + tr * 4 + i;
        if (row < N) *(float4*)&h2[(size_t)row * 64 + tc * 4] = acc[i];
    }
}

// ---------------- attention logits ----------------

__global__ void alpha1_kernel(const float* __restrict__ h1, const float* __restrict__ aw,
                              const float* __restrict__ dw, float* __restrict__ as1,
                              float* __restrict__ ad1, int N) {
    int t = blockIdx.x * blockDim.x + threadIdx.x;
    if (t >= N * 4) return;
    int n = t >> 2, h = t & 3;
    const float4* hp = (const float4*)(h1 + (size_t)n * 128 + h * 32);
    const float4* ap = (const float4*)(aw + h * 32);
    const float4* dp = (const float4*)(dw + h * 32);
    float s = 0.f, d = 0.f;
#pragma unroll
    for (int j = 0; j < 8; j++) {
        float4 v = hp[j], a = ap[j], dd = dp[j];
        s += v.x * a.x + v.y * a.y + v.z * a.z + v.w * a.w;
        d += v.x * dd.x + v.y * dd.y + v.z * dd.z + v.w * dd.w;
    }
    as1[t] = s;
    ad1[t] = d;
}

__global__ void alpha2_kernel(const float* __restrict__ h2, const float* __restrict__ aw,
                              const float* __restrict__ dw, float* __restrict__ as2,
                              float* __restrict__ ad2, int N) {
    int n = blockIdx.x * blockDim.x + threadIdx.x;
    if (n >= N) return;
    const float4* hp = (const float4*)(h2 + (size_t)n * 64);
    float s = 0.f, d = 0.f;
#pragma unroll
    for (int j = 0; j < 16; j++) {
        float4 v = hp[j];
        float4 a = ((const float4*)aw)[j];
        float4 dd = ((const float4*)dw)[j];
        s += v.x * a.x + v.y * a.y + v.z * a.z + v.w * a.w;
        d += v.x * dd.x + v.y * dd.y + v.z * dd.z + v.w * dd.w;
    }
    as2[n] = s;
    ad2[n] = d;
}

// ---------------- aggregation: online softmax per dst node ----------------

__global__ void __launch_bounds__(128)
agg1_kernel(const int* __restrict__ csr, const int* __restrict__ indptr,
            const int* __restrict__ counts, const float* __restrict__ as1,
            const float* __restrict__ ad1, const float* __restrict__ h1,
            const float* __restrict__ b1, float* __restrict__ x1, int N) {
    int n = blockIdx.x;
    int c = threadIdx.x;       // 0..127
    int h = c >> 5;            // head
    int start = indptr[n];
    int cnt = counts[n];
    float ad = ad1[n * 4 + h];
    float m = -INFINITY, l = 0.f, acc = 0.f;
    int src = csr[start];
    for (int i = 0; i < cnt; i++) {
        int nsrc = (i + 1 < cnt) ? csr[start + i + 1] : 0;
        float e = as1[src * 4 + h] + ad;
        e = (e > 0.f) ? e : NEG_SLOPE * e;
        float mn = fmaxf(m, e);
        float cf = __expf(m - mn);   // m=-inf first iter -> 0
        float p = __expf(e - mn);
        l = l * cf + p;
        acc = acc * cf + p * h1[(size_t)src * 128 + c];
        m = mn;
        src = nsrc;
    }
    float o = acc / l + b1[c];
    // ELU (alpha=1)
    x1[(size_t)n * 128 + c] = (o > 0.f) ? o : (__expf(o) - 1.f);
}

__global__ void __launch_bounds__(64)
agg2_kernel(const int* __restrict__ csr, const int* __restrict__ indptr,
            const int* __restrict__ counts, const float* __restrict__ as2,
            const float* __restrict__ ad2, const float* __restrict__ h2,
            const float* __restrict__ b2, float* __restrict__ out, int N) {
    int n = blockIdx.x;
    int c = threadIdx.x;       // 0..63
    int start = indptr[n];
    int cnt = counts[n];
    float ad = ad2[n];
    float m = -INFINITY, l = 0.f, acc = 0.f;
    int src = csr[start];
    for (int i = 0; i < cnt; i++) {
        int nsrc = (i + 1 < cnt) ? csr[start + i + 1] : 0;
        float e = as2[src] + ad;
        e = (e > 0.f) ? e : NEG_SLOPE * e;
        float mn = fmaxf(m, e);
        float cf = __expf(m - mn);
        float p = __expf(e - mn);
        l = l * cf + p;
        acc = acc * cf + p * h2[(size_t)src * 64 + c];
        m = mn;
        src = nsrc;
    }
    out[(size_t)n * 64 + c] = acc / l + b2[c];
}

// ---------------- launcher ----------------

extern "C" void kernel_launch(void* const* d_in, const int* in_sizes, int n_in,
                              void* d_out, int out_size, void* d_ws, size_t ws_size,
                              hipStream_t stream) {
    const int*   xidx = (const int*)d_in[0];
    const int*   ei   = (const int*)d_in[1];
    const float* emb  = (const float*)d_in[2];
    const float* W1   = (const float*)d_in[3];
    const float* a_s1 = (const float*)d_in[4];
    const float* a_d1 = (const float*)d_in[5];
    const float* b1   = (const float*)d_in[6];
    const float* W2   = (const float*)d_in[7];
    const float* a_s2 = (const float*)d_in[8];
    const float* a_d2 = (const float*)d_in[9];
    const float* b2   = (const float*)d_in[10];
    float* out = (float*)d_out;

    const int N  = in_sizes[0];
    const int E  = in_sizes[1] / 2;
    const int E2 = E + N;
    const int B  = (N + 255) / 256;   // scan chunks (391 for N=100000)

    // workspace layout
    int* ws_i   = (int*)d_ws;
    int* counts = ws_i;
    int* indptr = ws_i + N;
    int* cursor = ws_i + 2 * (size_t)N;
    int* bs     = ws_i + 3 * (size_t)N;
    int* csr    = ws_i + 3 * (size_t)N + 512;
    size_t fbase = ((size_t)(3 * (size_t)N + 512 + E2) + 3) & ~(size_t)3;
    float* ws_f = (float*)d_ws;
    float* h1  = ws_f + fbase;                  // N*128
    float* x1  = h1 + (size_t)N * 128;          // N*128
    float* as1 = x1 + (size_t)N * 128;          // N*4
    float* ad1 = as1 + (size_t)N * 4;           // N*4
    float* h2  = h1;   // alias: h1 dead after agg1
    float* as2 = as1;  // alias: as1 dead after agg1
    float* ad2 = ad1;

    // CSR build
    zero_kernel<<<(N + 255) / 256, 256, 0, stream>>>(counts, N);
    hist_kernel<<<(E2 + 255) / 256, 256, 0, stream>>>(ei, E, E2, counts);
    scan1_kernel<<<B, 256, 0, stream>>>(counts, N, indptr, bs);
    scan2_kernel<<<1, 512, 0, stream>>>(bs, B);
    scan3_kernel<<<(N + 255) / 256, 256, 0, stream>>>(indptr, cursor, bs, N);
    scatter_kernel<<<(E2 + 255) / 256, 256, 0, stream>>>(ei, E, E2, cursor, csr);

    // Layer 1
    {
        dim3 g((N + 63) / 64, 2);
        gemm1_kernel<<<g, 256, 0, stream>>>(emb, xidx, W1, h1, N);
    }
    alpha1_kernel<<<(N * 4 + 255) / 256, 256, 0, stream>>>(h1, a_s1, a_d1, as1, ad1, N);
    agg1_kernel<<<N, 128, 0, stream>>>(csr, indptr, counts, as1, ad1, h1, b1, x1, N);

    // Layer 2
    gemm2_kernel<<<(N + 63) / 64, 256, 0, stream>>>(x1, W2, h2, N);
    alpha2_kernel<<<(N + 255) / 256, 256, 0, stream>>>(h2, a_s2, a_d2, as2, ad2, N);
    agg2_kernel<<<N, 64, 0, stream>>>(csr, indptr, counts, as2, ad2, h2, b2, out, N);
}

// Round 3
// 642.969 us; speedup vs baseline: 1.4520x; 1.1771x over previous
//
#include <hip/hip_runtime.h>
#include <math.h>

// GATNet: N=100000 nodes, D=128, HEADS=4, HID=32, OUT_C=64, E=1.6M (+N self-loops)
#define NEG_SLOPE 0.2f

// ---------------- CSR build ----------------

__global__ void zero_kernel(int* __restrict__ p, int n) {
    int i = blockIdx.x * blockDim.x + threadIdx.x;
    if (i < n) p[i] = 0;
}

__global__ void hist_kernel(const int* __restrict__ ei, int E, int E2, int* __restrict__ counts) {
    int e = blockIdx.x * blockDim.x + threadIdx.x;
    if (e >= E2) return;
    int dst = (e < E) ? ei[E + e] : (e - E);   // self-loop tail
    atomicAdd(&counts[dst], 1);
}

// per-256-chunk exclusive scan; chunk totals to bs[]
__global__ void scan1_kernel(const int* __restrict__ counts, int N,
                             int* __restrict__ indptr, int* __restrict__ bs) {
    __shared__ int s[256];
    int t = threadIdx.x;
    int i = blockIdx.x * 256 + t;
    int v = (i < N) ? counts[i] : 0;
    s[t] = v;
    __syncthreads();
    for (int off = 1; off < 256; off <<= 1) {
        int u = (t >= off) ? s[t - off] : 0;
        __syncthreads();
        s[t] += u;
        __syncthreads();
    }
    if (i < N) indptr[i] = s[t] - v;      // exclusive within chunk
    if (t == 255) bs[blockIdx.x] = s[255]; // chunk total
}

// single-block exclusive scan of chunk totals (B <= 512)
__global__ void scan2_kernel(int* __restrict__ bs, int B) {
    __shared__ int s[512];
    int t = threadIdx.x;
    s[t] = (t < B) ? bs[t] : 0;
    __syncthreads();
    for (int off = 1; off < 512; off <<= 1) {
        int u = (t >= off) ? s[t - off] : 0;
        __syncthreads();
        s[t] += u;
        __syncthreads();
    }
    if (t < B) bs[t] = (t == 0) ? 0 : s[t - 1];
}

__global__ void scan3_kernel(int* __restrict__ indptr, int* __restrict__ cursor,
                             const int* __restrict__ bs, int N) {
    int i = blockIdx.x * blockDim.x + threadIdx.x;
    if (i >= N) return;
    int v = indptr[i] + bs[i >> 8];
    indptr[i] = v;
    cursor[i] = v;
}

__global__ void scatter_kernel(const int* __restrict__ ei, int E, int E2,
                               int* __restrict__ cursor, int* __restrict__ csr_src) {
    int e = blockIdx.x * blockDim.x + threadIdx.x;
    if (e >= E2) return;
    int src, dst;
    if (e < E) { src = ei[e]; dst = ei[E + e]; }
    else       { src = e - E; dst = e - E; }
    int pos = atomicAdd(&cursor[dst], 1);
    csr_src[pos] = src;
}

// ---------------- register-tiled fp32 GEMMs ----------------

__global__ __launch_bounds__(256) void gemm1_kernel(const float* __restrict__ emb,
                             const int* __restrict__ xidx,
                             const float* __restrict__ W1, float* __restrict__ h1, int N) {
    __shared__ float xs[64][128];
    __shared__ float ws[128][64];
    int tid = threadIdx.x;
    int r0 = blockIdx.x * 64;
    int c0 = blockIdx.y * 64;
    {   // stage W1 cols [c0, c0+64)
        const float4* W4 = (const float4*)W1;   // row stride 32 float4
        float4* ws4 = (float4*)ws;              // row stride 16 float4
        int cbase = c0 >> 2;
        for (int i = tid; i < 128 * 16; i += 256) {
            int k = i >> 4, c = i & 15;
            ws4[i] = W4[k * 32 + cbase + c];
        }
    }
    {   // stage x rows [r0, r0+64) with embedding gather
        float4* xs4 = (float4*)xs;
        for (int i = tid; i < 64 * 32; i += 256) {
            int r = i >> 5, c = i & 31;
            int row = r0 + r;
            float4 v = make_float4(0.f, 0.f, 0.f, 0.f);
            if (row < N) {
                int s = xidx[row];
                v = ((const float4*)emb)[(size_t)s * 32 + c];
            }
            xs4[i] = v;
        }
    }
    __syncthreads();
    int tr = tid >> 4;   // 0..15 -> rows tr*4..tr*4+3
    int tc = tid & 15;   // 0..15 -> cols tc*4..tc*4+3
    float4 acc[4];
    acc[0] = acc[1] = acc[2] = acc[3] = make_float4(0.f, 0.f, 0.f, 0.f);
    for (int k = 0; k < 128; k += 4) {
        float4 wv0 = *(const float4*)&ws[k][tc * 4];
        float4 wv1 = *(const float4*)&ws[k + 1][tc * 4];
        float4 wv2 = *(const float4*)&ws[k + 2][tc * 4];
        float4 wv3 = *(const float4*)&ws[k + 3][tc * 4];
#pragma unroll
        for (int i = 0; i < 4; i++) {
            float4 xv = *(const float4*)&xs[tr * 4 + i][k];
            acc[i].x = fmaf(xv.x, wv0.x, acc[i].x);
            acc[i].y = fmaf(xv.x, wv0.y, acc[i].y);
            acc[i].z = fmaf(xv.x, wv0.z, acc[i].z);
            acc[i].w = fmaf(xv.x, wv0.w, acc[i].w);
            acc[i].x = fmaf(xv.y, wv1.x, acc[i].x);
            acc[i].y = fmaf(xv.y, wv1.y, acc[i].y);
            acc[i].z = fmaf(xv.y, wv1.z, acc[i].z);
            acc[i].w = fmaf(xv.y, wv1.w, acc[i].w);
            acc[i].x = fmaf(xv.z, wv2.x, acc[i].x);
            acc[i].y = fmaf(xv.z, wv2.y, acc[i].y);
            acc[i].z = fmaf(xv.z, wv2.z, acc[i].z);
            acc[i].w = fmaf(xv.z, wv2.w, acc[i].w);
            acc[i].x = fmaf(xv.w, wv3.x, acc[i].x);
            acc[i].y = fmaf(xv.w, wv3.y, acc[i].y);
            acc[i].z = fmaf(xv.w, wv3.z, acc[i].z);
            acc[i].w = fmaf(xv.w, wv3.w, acc[i].w);
        }
    }
#pragma unroll
    for (int i = 0; i < 4; i++) {
        int row = r0 + tr * 4 + i;
        if (row < N) *(float4*)&h1[(size_t)row * 128 + c0 + tc * 4] = acc[i];
    }
}

__global__ __launch_bounds__(256) void gemm2_kernel(const float* __restrict__ x1,
                             const float* __restrict__ W2,
                             float* __restrict__ h2, int N) {
    __shared__ float xs[64][128];
    __shared__ float ws[128][64];
    int tid = threadIdx.x;
    int r0 = blockIdx.x * 64;
    {   // stage all of W2
        const float4* W4 = (const float4*)W2;
        float4* ws4 = (float4*)ws;
        for (int i = tid; i < 128 * 16; i += 256) ws4[i] = W4[i];
    }
    {   // stage x rows
        float4* xs4 = (float4*)xs;
        for (int i = tid; i < 64 * 32; i += 256) {
            int r = i >> 5, c = i & 31;
            int row = r0 + r;
            float4 v = make_float4(0.f, 0.f, 0.f, 0.f);
            if (row < N) v = ((const float4*)x1)[(size_t)row * 32 + c];
            xs4[i] = v;
        }
    }
    __syncthreads();
    int tr = tid >> 4;
    int tc = tid & 15;
    float4 acc[4];
    acc[0] = acc[1] = acc[2] = acc[3] = make_float4(0.f, 0.f, 0.f, 0.f);
    for (int k = 0; k < 128; k += 4) {
        float4 wv0 = *(const float4*)&ws[k][tc * 4];
        float4 wv1 = *(const float4*)&ws[k + 1][tc * 4];
        float4 wv2 = *(const float4*)&ws[k + 2][tc * 4];
        float4 wv3 = *(const float4*)&ws[k + 3][tc * 4];
#pragma unroll
        for (int i = 0; i < 4; i++) {
            float4 xv = *(const float4*)&xs[tr * 4 + i][k];
            acc[i].x = fmaf(xv.x, wv0.x, acc[i].x);
            acc[i].y = fmaf(xv.x, wv0.y, acc[i].y);
            acc[i].z = fmaf(xv.x, wv0.z, acc[i].z);
            acc[i].w = fmaf(xv.x, wv0.w, acc[i].w);
            acc[i].x = fmaf(xv.y, wv1.x, acc[i].x);
            acc[i].y = fmaf(xv.y, wv1.y, acc[i].y);
            acc[i].z = fmaf(xv.y, wv1.z, acc[i].z);
            acc[i].w = fmaf(xv.y, wv1.w, acc[i].w);
            acc[i].x = fmaf(xv.z, wv2.x, acc[i].x);
            acc[i].y = fmaf(xv.z, wv2.y, acc[i].y);
            acc[i].z = fmaf(xv.z, wv2.z, acc[i].z);
            acc[i].w = fmaf(xv.z, wv2.w, acc[i].w);
            acc[i].x = fmaf(xv.w, wv3.x, acc[i].x);
            acc[i].y = fmaf(xv.w, wv3.y, acc[i].y);
            acc[i].z = fmaf(xv.w, wv3.z, acc[i].z);
            acc[i].w = fmaf(xv.w, wv3.w, acc[i].w);
        }
    }
#pragma unroll
    for (int i = 0; i < 4; i++) {
        int row = r0 + tr * 4 + i;
        if (row < N) *(float4*)&h2[(size_t)row * 64 + tc * 4] = acc[i];
    }
}

// ---------------- attention logits ----------------

__global__ void alpha1_kernel(const float* __restrict__ h1, const float* __restrict__ aw,
                              const float* __restrict__ dw, float* __restrict__ as1,
                              float* __restrict__ ad1, int N) {
    int t = blockIdx.x * blockDim.x + threadIdx.x;
    if (t >= N * 4) return;
    int n = t >> 2, h = t & 3;
    const float4* hp = (const float4*)(h1 + (size_t)n * 128 + h * 32);
    const float4* ap = (const float4*)(aw + h * 32);
    const float4* dp = (const float4*)(dw + h * 32);
    float s = 0.f, d = 0.f;
#pragma unroll
    for (int j = 0; j < 8; j++) {
        float4 v = hp[j], a = ap[j], dd = dp[j];
        s += v.x * a.x + v.y * a.y + v.z * a.z + v.w * a.w;
        d += v.x * dd.x + v.y * dd.y + v.z * dd.z + v.w * dd.w;
    }
    as1[t] = s;
    ad1[t] = d;
}

__global__ void alpha2_kernel(const float* __restrict__ h2, const float* __restrict__ aw,
                              const float* __restrict__ dw, float* __restrict__ as2,
                              float* __restrict__ ad2, int N) {
    int n = blockIdx.x * blockDim.x + threadIdx.x;
    if (n >= N) return;
    const float4* hp = (const float4*)(h2 + (size_t)n * 64);
    float s = 0.f, d = 0.f;
#pragma unroll
    for (int j = 0; j < 16; j++) {
        float4 v = hp[j];
        float4 a = ((const float4*)aw)[j];
        float4 dd = ((const float4*)dw)[j];
        s += v.x * a.x + v.y * a.y + v.z * a.z + v.w * a.w;
        d += v.x * dd.x + v.y * dd.y + v.z * dd.z + v.w * dd.w;
    }
    as2[n] = s;
    ad2[n] = d;
}

// ---------------- aggregation: two-phase softmax per dst node ----------------
// Phase A: per-(node,head) softmax stats (m,l) from L2-resident as1 gathers.
// Phase B: per-edge weights computed ONCE into LDS, then pure gather-FMA.

__global__ void __launch_bounds__(128)
agg1_kernel(const int* __restrict__ csr, const int* __restrict__ indptr,
            const int* __restrict__ counts, const float* __restrict__ as1,
            const float* __restrict__ ad1, const float* __restrict__ h1,
            const float* __restrict__ b1, float* __restrict__ x1, int N) {
    __shared__ float ew[64 * 4];
    __shared__ int   ssrc[64];
    __shared__ float rm[128], rl[128];
    __shared__ float mf[4], li[4];
    int n = blockIdx.x;
    int tid = threadIdx.x;
    int start = indptr[n];
    int cnt = counts[n];
    int h = tid & 3;       // head for stats/weights
    int slot = tid >> 2;   // edge slot 0..31
    float ad = ad1[n * 4 + h];
    // Phase A: per-thread online (m,l) over strided edges
    float m = -1e30f, l = 0.f;
    for (int i = slot; i < cnt; i += 32) {
        int src = csr[start + i];
        float e = as1[src * 4 + h] + ad;
        e = (e > 0.f) ? e : NEG_SLOPE * e;
        float mn = fmaxf(m, e);
        l = l * __expf(m - mn) + __expf(e - mn);
        m = mn;
    }
    rm[tid] = m; rl[tid] = l;
    __syncthreads();
    // tree-reduce; offsets all multiples of 4 keep heads aligned
    for (int off = 64; off >= 4; off >>= 1) {
        if (tid < off) {
            float m2 = rm[tid + off], l2 = rl[tid + off];
            float m1 = rm[tid];
            float mn = fmaxf(m1, m2);
            rl[tid] = rl[tid] * __expf(m1 - mn) + l2 * __expf(m2 - mn);
            rm[tid] = mn;
        }
        __syncthreads();
    }
    if (tid < 4) { mf[tid] = rm[tid]; li[tid] = 1.f / rl[tid]; }
    __syncthreads();
    // Phase B
    int c = tid;           // channel 0..127
    int hh = tid >> 5;     // head for accumulation
    float acc = 0.f;
    for (int base = 0; base < cnt; base += 64) {
        int nn = min(64, cnt - base);
        for (int j = slot; j < nn; j += 32) {
            int src = csr[start + base + j];
            if (h == 0) ssrc[j] = src;
            float e = as1[src * 4 + h] + ad;
            e = (e > 0.f) ? e : NEG_SLOPE * e;
            ew[j * 4 + h] = __expf(e - mf[h]) * li[h];
        }
        __syncthreads();
        int j = 0;
        for (; j + 4 <= nn; j += 4) {
            int s0 = ssrc[j], s1 = ssrc[j + 1], s2 = ssrc[j + 2], s3 = ssrc[j + 3];
            float w0 = ew[j * 4 + hh], w1 = ew[(j + 1) * 4 + hh];
            float w2 = ew[(j + 2) * 4 + hh], w3 = ew[(j + 3) * 4 + hh];
            float v0 = h1[(size_t)s0 * 128 + c];
            float v1 = h1[(size_t)s1 * 128 + c];
            float v2 = h1[(size_t)s2 * 128 + c];
            float v3 = h1[(size_t)s3 * 128 + c];
            acc = fmaf(w0, v0, acc);
            acc = fmaf(w1, v1, acc);
            acc = fmaf(w2, v2, acc);
            acc = fmaf(w3, v3, acc);
        }
        for (; j < nn; j++) {
            acc = fmaf(ew[j * 4 + hh], h1[(size_t)ssrc[j] * 128 + c], acc);
        }
        __syncthreads();
    }
    float o = acc + b1[c];
    x1[(size_t)n * 128 + c] = (o > 0.f) ? o : (__expf(o) - 1.f);   // ELU
}

// agg2: 2 nodes per 128-thread block, one wave per node, shuffle-broadcast
// weights (no LDS, no barriers -> no cross-node barrier divergence).
__global__ void __launch_bounds__(128)
agg2_kernel(const int* __restrict__ csr, const int* __restrict__ indptr,
            const int* __restrict__ counts, const float* __restrict__ as2,
            const float* __restrict__ ad2, const float* __restrict__ h2,
            const float* __restrict__ b2, float* __restrict__ out, int N) {
    int wave = threadIdx.x >> 6;
    int lane = threadIdx.x & 63;
    int n = blockIdx.x * 2 + wave;
    if (n >= N) return;
    int start = indptr[n];
    int cnt = counts[n];
    float ad = ad2[n];
    // Phase A: online (m,l) per lane, then wave butterfly reduce
    float m = -1e30f, l = 0.f;
    for (int i = lane; i < cnt; i += 64) {
        float e = as2[csr[start + i]] + ad;
        e = (e > 0.f) ? e : NEG_SLOPE * e;
        float mn = fmaxf(m, e);
        l = l * __expf(m - mn) + __expf(e - mn);
        m = mn;
    }
    for (int off = 32; off >= 1; off >>= 1) {
        float m2 = __shfl_xor(m, off);
        float l2 = __shfl_xor(l, off);
        float mn = fmaxf(m, m2);
        l = l * __expf(m - mn) + l2 * __expf(m2 - mn);
        m = mn;
    }
    float inv = 1.f / l;
    // Phase B: weights in registers, broadcast via shuffle
    float acc = 0.f;
    int c = lane;
    for (int base = 0; base < cnt; base += 64) {
        int nn = min(64, cnt - base);
        int srcr = 0; float wr = 0.f;
        if (lane < nn) {
            srcr = csr[start + base + lane];
            float e = as2[srcr] + ad;
            e = (e > 0.f) ? e : NEG_SLOPE * e;
            wr = __expf(e - m) * inv;
        }
        int j = 0;
        for (; j + 4 <= nn; j += 4) {
            int s0 = __shfl(srcr, j), s1 = __shfl(srcr, j + 1);
            int s2 = __shfl(srcr, j + 2), s3 = __shfl(srcr, j + 3);
            float w0 = __shfl(wr, j), w1 = __shfl(wr, j + 1);
            float w2 = __shfl(wr, j + 2), w3 = __shfl(wr, j + 3);
            float v0 = h2[(size_t)s0 * 64 + c];
            float v1 = h2[(size_t)s1 * 64 + c];
            float v2 = h2[(size_t)s2 * 64 + c];
            float v3 = h2[(size_t)s3 * 64 + c];
            acc = fmaf(w0, v0, acc);
            acc = fmaf(w1, v1, acc);
            acc = fmaf(w2, v2, acc);
            acc = fmaf(w3, v3, acc);
        }
        for (; j < nn; j++) {
            acc = fmaf(__shfl(wr, j), h2[(size_t)__shfl(srcr, j) * 64 + c], acc);
        }
    }
    out[(size_t)n * 64 + c] = acc + b2[c];
}

// ---------------- launcher ----------------

extern "C" void kernel_launch(void* const* d_in, const int* in_sizes, int n_in,
                              void* d_out, int out_size, void* d_ws, size_t ws_size,
                              hipStream_t stream) {
    const int*   xidx = (const int*)d_in[0];
    const int*   ei   = (const int*)d_in[1];
    const float* emb  = (const float*)d_in[2];
    const float* W1   = (const float*)d_in[3];
    const float* a_s1 = (const float*)d_in[4];
    const float* a_d1 = (const float*)d_in[5];
    const float* b1   = (const float*)d_in[6];
    const float* W2   = (const float*)d_in[7];
    const float* a_s2 = (const float*)d_in[8];
    const float* a_d2 = (const float*)d_in[9];
    const float* b2   = (const float*)d_in[10];
    float* out = (float*)d_out;

    const int N  = in_sizes[0];
    const int E  = in_sizes[1] / 2;
    const int E2 = E + N;
    const int B  = (N + 255) / 256;   // scan chunks (391 for N=100000)

    // workspace layout
    int* ws_i   = (int*)d_ws;
    int* counts = ws_i;
    int* indptr = ws_i + N;
    int* cursor = ws_i + 2 * (size_t)N;
    int* bs     = ws_i + 3 * (size_t)N;
    int* csr    = ws_i + 3 * (size_t)N + 512;
    size_t fbase = ((size_t)(3 * (size_t)N + 512 + E2) + 3) & ~(size_t)3;
    float* ws_f = (float*)d_ws;
    float* h1  = ws_f + fbase;                  // N*128
    float* x1  = h1 + (size_t)N * 128;          // N*128
    float* as1 = x1 + (size_t)N * 128;          // N*4
    float* ad1 = as1 + (size_t)N * 4;           // N*4
    float* h2  = h1;   // alias: h1 dead after agg1
    float* as2 = as1;  // alias: as1 dead after agg1
    float* ad2 = ad1;

    // CSR build
    zero_kernel<<<(N + 255) / 256, 256, 0, stream>>>(counts, N);
    hist_kernel<<<(E2 + 255) / 256, 256, 0, stream>>>(ei, E, E2, counts);
    scan1_kernel<<<B, 256, 0, stream>>>(counts, N, indptr, bs);
    scan2_kernel<<<1, 512, 0, stream>>>(bs, B);
    scan3_kernel<<<(N + 255) / 256, 256, 0, stream>>>(indptr, cursor, bs, N);
    scatter_kernel<<<(E2 + 255) / 256, 256, 0, stream>>>(ei, E, E2, cursor, csr);

    // Layer 1
    {
        dim3 g((N + 63) / 64, 2);
        gemm1_kernel<<<g, 256, 0, stream>>>(emb, xidx, W1, h1, N);
    }
    alpha1_kernel<<<(N * 4 + 255) / 256, 256, 0, stream>>>(h1, a_s1, a_d1, as1, ad1, N);
    agg1_kernel<<<N, 128, 0, stream>>>(csr, indptr, counts, as1, ad1, h1, b1, x1, N);

    // Layer 2
    gemm2_kernel<<<(N + 63) / 64, 256, 0, stream>>>(x1, W2, h2, N);
    alpha2_kernel<<<(N + 255) / 256, 256, 0, stream>>>(h2, a_s2, a_d2, as2, ad2, N);
    agg2_kernel<<<(N + 1) / 2, 128, 0, stream>>>(csr, indptr, counts, as2, ad2, h2, b2, out, N);
}